// Round 9
// baseline (1276.781 us; speedup 1.0000x reference)
//
#include <hip/hip_runtime.h>

// LSTM decoder, MI355X. Persistent recurrence, round 14.
// r13 post-mortem: tag fabric free, but r11==r13==5.3us/step -> shared term
// = coherent-read BW: every block pulls all 128KB of h with L2-bypass loads
// (16K lines/XCD/step, 16x duplication). r14: tag-verified two-hop staging:
//  - per XCD, block rank rk pulls slice rk (512 units, 8KB) sc0sc1 + tag
//    verify + retry (1K lines/XCD/step), plain-stores into per-XCD parity-
//    slotted staging (plain store -> L2 visibility proven by r9).
//  - consumers: buffer_inv sc0 (L1-only) + PLAIN loads of staged units +
//    per-unit tag check; stale -> cheap L2-speed retry with L1-inv.
//  - no joins anywhere; stg stale-init gives wrong-tag on first touch;
//    own-block units still substituted from hloc (LDS).
//  - stager pull issued before act-GEMM waits (LLC latency hides under act
//    MFMAs). All loop VMEM is counted inline asm; raw s_barrier only.
// L=128, B=64, IN_F=ACT_F=512, H=1024.

#define LSTEPS 128
#define B 64
#define ACTF 512
#define H 1024
#define NB 128
#define HC 8
#define GSTR 37            // f32 leading dim of per-wave gate regions

typedef short s16x8 __attribute__((ext_vector_type(8)));
typedef short s16x4 __attribute__((ext_vector_type(4)));
typedef float f32x4 __attribute__((ext_vector_type(4)));
typedef unsigned short u16;
typedef unsigned long long u64;

__device__ __forceinline__ u16 f2bf(float f) {
  return __builtin_bit_cast(u16, (__bf16)f);   // RNE
}
__device__ __forceinline__ float sigm(float x) { return 1.f / (1.f + __expf(-x)); }
__device__ __forceinline__ float tanh_fast(float x) { return 2.f / (1.f + __expf(-2.f * x)) - 1.f; }

// ---- merged setup kernel ----
__global__ void k_setup(const float* __restrict__ act, u16* __restrict__ actb,
                        const float* __restrict__ Wih, const float* __restrict__ Whh,
                        u16* __restrict__ wg,
                        const float* __restrict__ h0, u16* __restrict__ hbp,
                        u16* __restrict__ stg, unsigned* __restrict__ xctr,
                        const float* __restrict__ inf, const float* __restrict__ bih,
                        const float* __restrict__ bhh, float* __restrict__ pre0) {
  const int bb = blockIdx.x;
  const int tid = threadIdx.x;
  if (bb < 2048) {                                   // act fp32 -> bf16, blocked [t][ch][m][8]
    int id = bb * 256 + tid;
    const float4* s = (const float4*)act + (size_t)id * 2;
    float4 a = s[0], b = s[1];
    s16x8 o;
    o[0] = (short)f2bf(a.x); o[1] = (short)f2bf(a.y); o[2] = (short)f2bf(a.z); o[3] = (short)f2bf(a.w);
    o[4] = (short)f2bf(b.x); o[5] = (short)f2bf(b.y); o[6] = (short)f2bf(b.z); o[7] = (short)f2bf(b.w);
    int t = id >> 12, m = (id >> 6) & 63, ch = id & 63;
    ((s16x8*)actb)[t * 4096 + ch * 64 + m] = o;
  } else if (bb < 5120) {                            // W fragments (unchanged)
    int idx = (bb - 2048) * 256 + tid;
    int bk = idx / 6144;
    int lin = idx - bk * 6144;
    int kt = lin >> 7, T = (lin >> 6) & 1, lane = lin & 63;
    int q = lane >> 4, r = lane & 15;
    int local = T * 16 + r;
    int j = (local >> 3) * 1024 + bk * 8 + (local & 7);
    int k = kt * 32 + q * 8;
    const float* src = (k < 512) ? (Wih + (size_t)j * 1024 + 512 + k)
                                 : (Whh + (size_t)j * 1024 + (k - 512));
    s16x8 o;
#pragma unroll
    for (int e = 0; e < 8; ++e) o[e] = (short)f2bf(src[e]);
    ((s16x8*)wg)[(size_t)bk * 6144 + lin] = o;
  } else if (bb < 5152) {                            // h0 -> tagged bf16 units, hbp slot 1
    int id = (bb - 5120) * 256 + tid;                // 0..8191 = unit (blk2,row)
    int blk2 = id >> 6, row = id & 63;
    const float* s = h0 + (size_t)row * H + blk2 * 8;
    s16x8 o;
#pragma unroll
    for (int e = 0; e < 8; ++e) o[e] = (short)f2bf(s[e]);
    o[0] = (short)((o[0] & ~1) | 1);                 // tag=1 (expected at t=0)
    ((s16x8*)(hbp + 65536))[blk2 * 64 + row] = o;
  } else if (bb < 5184) {                            // hbp slot 0 stale init (LSB=1)
    int id = (bb - 5152) * 256 + tid;
    s16x8 p;
#pragma unroll
    for (int e = 0; e < 8; ++e) p[e] = 1;
    ((s16x8*)hbp)[id] = p;
    if (bb == 5152 && tid < 8) xctr[tid] = 0u;
  } else if (bb < 5312) {                            // stg stale init (wrong-tag per slot)
    int id = (bb - 5184) * 256 + tid;                // 0..32767, 4 units each
#pragma unroll
    for (int e = 0; e < 4; ++e) {
      int uu = id * 4 + e;                           // unit in [0,131072)
      int par = (uu >> 13) & 1;                      // 8192 units per (xcc,par)
      short lsb = (short)(1 ^ par);                  // par0 first used with tag0 -> init 1
      s16x8 p;                                       // par1 first used with tag1 -> init 0
#pragma unroll
      for (int k2 = 0; k2 < 8; ++k2) p[k2] = lsb;
      ((s16x8*)stg)[uu] = p;
    }
  } else {                                           // PRE0
    int o = (bb - 5312) * 256 + tid;
    int bk = o >> 11;
    int rr = o & 2047;
    int b = rr >> 5;
    int local = rr & 31;
    int j = (local >> 3) * 1024 + bk * 8 + (local & 7);
    const float4* xa = (const float4*)(inf + (size_t)b * 512);
    const float4* wa = (const float4*)(Wih + (size_t)j * 1024);
    float s = 0.f;
#pragma unroll 4
    for (int k = 0; k < 128; ++k) {
      float4 x = xa[k], w = wa[k];
      s += x.x * w.x + x.y * w.y + x.z * w.z + x.w * w.w;
    }
    pre0[o] = s + bih[j] + bhh[j];
  }
}

// ---- asm helpers (all loop VMEM is asm so vmcnt counting is exact) ----
#define AISS(dst, ptr) \
  asm volatile("global_load_dwordx4 %0, %1, off" : "=v"(dst) : "v"(ptr) : "memory");
#define PISS(dst, ptr) \
  asm volatile("global_load_dwordx4 %0, %1, off" : "=v"(dst) : "v"(ptr) : "memory");
#define HISS(dst, ptr) \
  asm volatile("global_load_dwordx4 %0, %1, off sc0 sc1" : "=v"(dst) : "v"(ptr) : "memory");
#define WAITV(N) { asm volatile("s_waitcnt vmcnt(" #N ")" ::: "memory"); \
                   __builtin_amdgcn_sched_barrier(0); }
#define LGKM0()  { asm volatile("s_waitcnt lgkmcnt(0)" ::: "memory"); }

// ---- persistent recurrent kernel ----
__global__ void __launch_bounds__(256, 1) k_rnn(
    const u16* __restrict__ actb, const u16* __restrict__ wg,
    const float* __restrict__ pre0, const float* __restrict__ cinit,
    u16* __restrict__ hbp, u16* __restrict__ stg,
    unsigned* __restrict__ xctr, unsigned* __restrict__ dump,
    float* __restrict__ out) {
  extern __shared__ char smem[];
  u16* wlds  = (u16*)smem;                          // 98304 B: W fragments
  float* gl  = (float*)(smem + 98304);              // 37888 B: 4 x 64 x 37 f32
  u16* hloc  = (u16*)(smem + 98304 + 37888);        // 1024 B: own tagged h units
  __shared__ int s_xcc, s_rank;

  const int tid = threadIdx.x;
  const int bk = blockIdx.x;
  const int w = tid >> 6;
  const int lane = tid & 63;
  const int q = lane >> 4, r = lane & 15;
  const int n0 = bk * HC;
  const int prow = tid >> 1, pcg = (tid & 1) * 4;

  if (tid == 0) {                        // XCD discovery + slice-rank election
    unsigned xcc;
    asm volatile("s_getreg_b32 %0, hwreg(HW_REG_XCC_ID)" : "=s"(xcc));
    xcc &= 7u;
    s_xcc = (int)xcc;
    s_rank = (int)atomicAdd(&xctr[xcc], 1u);
  }

  {
    const s16x8* src = (const s16x8*)wg + (size_t)bk * 6144;
    s16x8* dst = (s16x8*)wlds;
    for (int i = tid; i < 6144; i += 256) dst[i] = src[i];
  }

  float pr4[16], cr[4];
  if (tid < 128) {
#pragma unroll
    for (int g = 0; g < 4; ++g)
#pragma unroll
      for (int e = 0; e < 4; ++e)
        pr4[g * 4 + e] = pre0[bk * 2048 + prow * 32 + g * 8 + pcg + e];
#pragma unroll
    for (int e = 0; e < 4; ++e) cr[e] = cinit[prow * H + n0 + pcg + e];
  }
  if (tid < 64)   // own h0 units (tagged, from hbp slot 1) into hloc
    *(s16x8*)(hloc + tid * 8) = ((const s16x8*)(hbp + 65536))[bk * 64 + tid];

  const bool ownw = (w == (bk >> 5));
  const int kown = (bk >> 2) & 7;
  const int qown = bk & 3;

  asm volatile("s_waitcnt vmcnt(0) lgkmcnt(0)" ::: "memory");
  __builtin_amdgcn_s_barrier();
  const int xcc = s_xcc;
  const int rk = s_rank;
  u16* stgx = stg + (size_t)xcc * 131072;   // this XCD's 2-slot staging (u16)

  f32x4 hv_prev = {0.f, 0.f, 0.f, 0.f};

  for (int t = 0; t < LSTEPS; ++t) {
    const int par = (t - 1) & 1;
    const int wtag = ((t - 1) >> 1) & 1;

    // ---- issue acts (16 loads/wave, plain cached) ----
    s16x8 af[4][4];
    const u16* ab = actb + (size_t)t * 32768 + (w * 4) * 2048 + q * 512 + r * 8;
#define AISSG(KK) \
    AISS(af[KK][0], ab + (KK) * 2048);       AISS(af[KK][1], ab + (KK) * 2048 + 128); \
    AISS(af[KK][2], ab + (KK) * 2048 + 256); AISS(af[KK][3], ab + (KK) * 2048 + 384);
    AISSG(0) AISSG(1) AISSG(2) AISSG(3)
#undef AISSG

    // ---- publication of h(t-1)/out(t-1): exactly 2 stores per wave ----
    if (t > 0) {
      if (w == 0) {                       // whole tagged 16B unit from hloc
        s16x8 hu0 = *(const s16x8*)(hloc + lane * 8);
        u16* hp = hbp + (size_t)par * 65536 + (size_t)bk * 512 + lane * 8;
        asm volatile("global_store_dwordx4 %0, %1, off sc0 sc1" :: "v"(hp), "v"(hu0) : "memory");
      } else {
        unsigned* dp = dump + ((bk & 15) * 64) + lane;
        asm volatile("global_store_dword %0, %1, off" :: "v"(dp), "v"(0u) : "memory");
      }
      if (tid < 128) {
        float* op = out + (size_t)(t - 1) * 65536 + (size_t)prow * H + n0 + pcg;
        asm volatile("global_store_dwordx4 %0, %1, off" :: "v"(op), "v"(hv_prev) : "memory");
      } else {
        unsigned* dp = dump + ((bk & 15) * 64) + lane;
        asm volatile("global_store_dword %0, %1, off" :: "v"(dp), "v"(0u) : "memory");
      }
    } else {
      unsigned* dp = dump + ((bk & 15) * 64) + lane;
      asm volatile("global_store_dword %0, %1, off" :: "v"(dp), "v"(0u) : "memory");
      asm volatile("global_store_dword %0, %1, off" :: "v"(dp), "v"(0u) : "memory");
    }

    f32x4 acc[4][2];
#pragma unroll
    for (int mt = 0; mt < 4; ++mt) {
      f32x4 z = {0.f, 0.f, 0.f, 0.f};
      acc[mt][0] = z; acc[mt][1] = z;
    }

    // ---- act-GEMM: waits {14,10,6,2} (acts oldest; stores never waited) ----
#define ACTCH(KK, VC) { \
      const s16x8* wb_ = (const s16x8*)wlds + (w * 4 + (KK)) * 128; \
      s16x8 b0_ = wb_[lane]; s16x8 b1_ = wb_[64 + lane]; \
      WAITV(VC) \
      acc[0][0] = __builtin_amdgcn_mfma_f32_16x16x32_bf16(af[KK][0], b0_, acc[0][0], 0, 0, 0); \
      acc[0][1] = __builtin_amdgcn_mfma_f32_16x16x32_bf16(af[KK][0], b1_, acc[0][1], 0, 0, 0); \
      acc[1][0] = __builtin_amdgcn_mfma_f32_16x16x32_bf16(af[KK][1], b0_, acc[1][0], 0, 0, 0); \
      acc[1][1] = __builtin_amdgcn_mfma_f32_16x16x32_bf16(af[KK][1], b1_, acc[1][1], 0, 0, 0); \
      acc[2][0] = __builtin_amdgcn_mfma_f32_16x16x32_bf16(af[KK][2], b0_, acc[2][0], 0, 0, 0); \
      acc[2][1] = __builtin_amdgcn_mfma_f32_16x16x32_bf16(af[KK][2], b1_, acc[2][1], 0, 0, 0); \
      acc[3][0] = __builtin_amdgcn_mfma_f32_16x16x32_bf16(af[KK][3], b0_, acc[3][0], 0, 0, 0); \
      acc[3][1] = __builtin_amdgcn_mfma_f32_16x16x32_bf16(af[KK][3], b1_, acc[3][1], 0, 0, 0); \
    }
    ACTCH(0, 14) ACTCH(1, 10) ACTCH(2, 6) ACTCH(3, 2)
#undef ACTCH

    // ---- stager: pull slice rk of h(t-1) from LLC (tag-verified), stage
    //      into own-XCD L2 via plain stores. 1K coherent lines/XCD/step. ----
    if (rk < 16) {
      const u16* sp0 = hbp + (size_t)par * 65536 + ((size_t)rk * 512 + tid) * 8;
      const u16* sp1 = sp0 + 2048;                 // +256 units
      u16* dd0 = stgx + (size_t)par * 65536 + ((size_t)rk * 512 + tid) * 8;
      u16* dd1 = dd0 + 2048;
      s16x8 v0, v1;
      unsigned g = 0;
      for (;;) {
        HISS(v0, sp0) HISS(v1, sp1) WAITV(0)       // also drains the 2 stores
        int ok = (((v0[0] ^ wtag) | (v1[0] ^ wtag)) & 1) == 0;
        if (__all(ok)) break;
        if (++g > 2048u) break;                    // wrong-answer beats hang
      }
      *(s16x8*)dd0 = v0;
      *(s16x8*)dd1 = v1;
    }
    WAITV(0)                                       // staging stores at L2
    asm volatile("buffer_inv sc0" ::: "memory");   // drop stale L1 lines

    // ---- h(t-1) burst: 32 PLAIN loads of staged units (L2-hit path) ----
    const u16* hb2 = stgx + (size_t)par * 65536 + ((w * 8) * 4 + q) * 512 + r * 8;
    s16x8 hu[8][4];
#define PISSG(I) \
    PISS(hu[I][0], hb2 + (I) * 2048)       PISS(hu[I][1], hb2 + (I) * 2048 + 128) \
    PISS(hu[I][2], hb2 + (I) * 2048 + 256) PISS(hu[I][3], hb2 + (I) * 2048 + 384)
    PISSG(0) PISSG(1) PISSG(2) PISSG(3) PISSG(4) PISSG(5) PISSG(6) PISSG(7)

#define SUBST(I) \
    if (ownw && (I) == kown && q == qown) { \
      hu[I][0] = *(const s16x8*)(hloc + (r +  0) * 8); \
      hu[I][1] = *(const s16x8*)(hloc + (r + 16) * 8); \
      hu[I][2] = *(const s16x8*)(hloc + (r + 32) * 8); \
      hu[I][3] = *(const s16x8*)(hloc + (r + 48) * 8); \
    }
#define CHECKOK(I, OK) { int bad_ = 0; \
      bad_ |= (hu[I][0][0] ^ wtag); bad_ |= (hu[I][1][0] ^ wtag); \
      bad_ |= (hu[I][2][0] ^ wtag); bad_ |= (hu[I][3][0] ^ wtag); \
      OK = ((bad_ & 1) == 0); }
#define DOMFMA(I) { \
      const s16x8* wb_ = (const s16x8*)wlds + (16 + w * 8 + (I)) * 128; \
      s16x8 b0_ = wb_[lane]; s16x8 b1_ = wb_[64 + lane]; \
      acc[0][0] = __builtin_amdgcn_mfma_f32_16x16x32_bf16(hu[I][0], b0_, acc[0][0], 0, 0, 0); \
      acc[0][1] = __builtin_amdgcn_mfma_f32_16x16x32_bf16(hu[I][0], b1_, acc[0][1], 0, 0, 0); \
      acc[1][0] = __builtin_amdgcn_mfma_f32_16x16x32_bf16(hu[I][1], b0_, acc[1][0], 0, 0, 0); \
      acc[1][1] = __builtin_amdgcn_mfma_f32_16x16x32_bf16(hu[I][1], b1_, acc[1][1], 0, 0, 0); \
      acc[2][0] = __builtin_amdgcn_mfma_f32_16x16x32_bf16(hu[I][2], b0_, acc[2][0], 0, 0, 0); \
      acc[2][1] = __builtin_amdgcn_mfma_f32_16x16x32_bf16(hu[I][2], b1_, acc[2][1], 0, 0, 0); \
      acc[3][0] = __builtin_amdgcn_mfma_f32_16x16x32_bf16(hu[I][3], b0_, acc[3][0], 0, 0, 0); \
      acc[3][1] = __builtin_amdgcn_mfma_f32_16x16x32_bf16(hu[I][3], b1_, acc[3][1], 0, 0, 0); \
    }

    unsigned stale = 0;
#define KSTEP(I, VC) { WAITV(VC) SUBST(I) int ok_; CHECKOK(I, ok_) \
      if (__all(ok_)) { DOMFMA(I) } else stale |= (1u << (I)); }
    KSTEP(0, 28) KSTEP(1, 24) KSTEP(2, 20) KSTEP(3, 16)
    KSTEP(4, 12) KSTEP(5, 8)  KSTEP(6, 4)  KSTEP(7, 0)
#undef KSTEP

    // ---- retry: L1-inv + re-read staged units (L2-speed; no global wait) ----
    unsigned guard = 0;
    while (stale) {
      if (++guard > 512u) break;   // wrong-answer beats hang
      asm volatile("buffer_inv sc0" ::: "memory");
      if (stale & 0x01u) { PISSG(0) } if (stale & 0x02u) { PISSG(1) }
      if (stale & 0x04u) { PISSG(2) } if (stale & 0x08u) { PISSG(3) }
      if (stale & 0x10u) { PISSG(4) } if (stale & 0x20u) { PISSG(5) }
      if (stale & 0x40u) { PISSG(6) } if (stale & 0x80u) { PISSG(7) }
      WAITV(0)
#define RETRY(I, M) if (stale & (M)) { SUBST(I) int ok_; CHECKOK(I, ok_) \
        if (__all(ok_)) { DOMFMA(I) stale &= ~(M); } }
      RETRY(0, 0x01u) RETRY(1, 0x02u) RETRY(2, 0x04u) RETRY(3, 0x08u)
      RETRY(4, 0x10u) RETRY(5, 0x20u) RETRY(6, 0x40u) RETRY(7, 0x80u)
#undef RETRY
    }
#undef PISSG
#undef SUBST
#undef CHECKOK
#undef DOMFMA

    // ---- phase 5: per-wave gate regions (GSTR=37) ----
    {
      float* glw = gl + w * (64 * GSTR);
#pragma unroll
      for (int mt = 0; mt < 4; ++mt) {
        const int bb2 = mt * 16 + q * 4;
#pragma unroll
        for (int T = 0; T < 2; ++T) {
          const int lc = T * 16 + r;
#pragma unroll
          for (int e = 0; e < 4; ++e)
            glw[(bb2 + e) * GSTR + lc] = acc[mt][T][e];
        }
      }
    }
    LGKM0()
    __builtin_amdgcn_s_barrier();        // (A) raw: no vmcnt drain

    // ---- phase 6: pointwise; h kept in regs + tagged bf16 unit in hloc ----
    if (tid < 128) {
      const float* base = gl + prow * GSTR + pcg;
      f32x4 s0 = *(const f32x4*)(base);
      f32x4 s1 = *(const f32x4*)(base + 8);
      f32x4 s2 = *(const f32x4*)(base + 16);
      f32x4 s3 = *(const f32x4*)(base + 24);
#pragma unroll
      for (int ww = 1; ww < 4; ++ww) {
        const float* b2 = base + ww * (64 * GSTR);
        s0 += *(const f32x4*)(b2);
        s1 += *(const f32x4*)(b2 + 8);
        s2 += *(const f32x4*)(b2 + 16);
        s3 += *(const f32x4*)(b2 + 24);
      }
      float hv[4];
#pragma unroll
      for (int e = 0; e < 4; ++e) {
        float ig = sigm(s0[e] + pr4[e]);
        float fg = sigm(s1[e] + pr4[4 + e]);
        float gg = tanh_fast(s2[e] + pr4[8 + e]);
        float og = sigm(s3[e] + pr4[12 + e]);
        cr[e] = fg * cr[e] + ig * gg;
        hv[e] = og * tanh_fast(cr[e]);
        hv_prev[e] = hv[e];
      }
      const int ptag = (t >> 1) & 1;
      s16x4 hb;
      hb[0] = (short)f2bf(hv[0]); hb[1] = (short)f2bf(hv[1]);
      hb[2] = (short)f2bf(hv[2]); hb[3] = (short)f2bf(hv[3]);
      if (pcg == 0) hb[0] = (short)((hb[0] & ~1) | ptag);
      *(s16x4*)(hloc + prow * 8 + pcg) = hb;
    }
    LGKM0()
    __builtin_amdgcn_s_barrier();        // (B) raw
  }

  // ---- epilogue: out[127], h_n, c_n ----
  if (tid < 128) {
    *(f32x4*)(out + (size_t)(LSTEPS - 1) * 65536 + (size_t)prow * H + n0 + pcg) = hv_prev;
    float* hn = out + (size_t)LSTEPS * 65536;
    float* cn = hn + 65536;
    *(f32x4*)(hn + (size_t)prow * H + n0 + pcg) = hv_prev;
    f32x4 cr4; cr4[0] = cr[0]; cr4[1] = cr[1]; cr4[2] = cr[2]; cr4[3] = cr[3];
    *(f32x4*)(cn + (size_t)prow * H + n0 + pcg) = cr4;
  }
}

extern "C" void kernel_launch(void* const* d_in, const int* in_sizes, int n_in,
                              void* d_out, int out_size, void* d_ws, size_t ws_size,
                              hipStream_t stream) {
  const float* inf = (const float*)d_in[0];
  const float* act = (const float*)d_in[1];
  const float* h0  = (const float*)d_in[2];
  const float* cst = (const float*)d_in[3];
  const float* Wih = (const float*)d_in[4];
  const float* Whh = (const float*)d_in[5];
  const float* bih = (const float*)d_in[6];
  const float* bhh = (const float*)d_in[7];
  float* out = (float*)d_out;

  char* ws = (char*)d_ws;
  u16* actb      = (u16*)ws;                    //  8,388,608 B
  u16* wg        = (u16*)(ws + 8388608);        // 12,582,912 B
  float* pre0    = (float*)(ws + 20971520);     //  1,048,576 B
  u16* hbp       = (u16*)(ws + 22020096);       //    262,144 B (2 slot x 128 blk x 512B)
  u16* stg       = (u16*)(ws + 22282240);       //  2,097,152 B (8 XCD x 2 slot x 128KB)
  unsigned* dump = (unsigned*)(ws + 24379392);  //      4,096 B (dummy-store sink)
  unsigned* xctr = (unsigned*)(ws + 24383488);  //         32 B (rank election)

  hipLaunchKernelGGL(k_setup, dim3(6336), dim3(256), 0, stream,
                     act, actb, Wih, Whh, wg, h0, hbp, stg, xctr,
                     inf, bih, bhh, pre0);

  // LDS: 98304 (W) + 37888 (gates) + 1024 (hloc) = 137216 B
  hipFuncSetAttribute((const void*)k_rnn, hipFuncAttributeMaxDynamicSharedMemorySize, 137216);
  hipLaunchKernelGGL(k_rnn, dim3(NB), dim3(256), 137216, stream,
                     actb, wg, pre0, cst, hbp, stg, xctr, dump, out);
}